// Round 12
// baseline (658.665 us; speedup 1.0000x reference)
//
#include <hip/hip_runtime.h>
#include <hip/hip_bf16.h>

typedef __bf16 bf16;
typedef __attribute__((ext_vector_type(8))) __bf16 bf16x8;
typedef __attribute__((ext_vector_type(4))) __bf16 bf16x4;
typedef __attribute__((ext_vector_type(4))) float f32x4;

#define B_ 128
#define L_ 8
#define T_ 48
#define V_ 10000
#define NBLK_REC 32
#define NBLK_ATT 16
#define NBLK_TOT 240
#define NWG 192            // GEMM worker blocks (blockIdx 48..239)

__device__ __forceinline__ float sigf(float x) { return 1.f / (1.f + expf(-x)); }

__device__ __forceinline__ void gl_lds16(const bf16* g, bf16* l) {
  __builtin_amdgcn_global_load_lds(
      (const __attribute__((address_space(1))) unsigned int*)g,
      (__attribute__((address_space(3))) unsigned int*)l, 16, 0, 0);
}

__device__ __forceinline__ unsigned aload32(const void* p) {
  return __hip_atomic_load((unsigned*)p, __ATOMIC_RELAXED, __HIP_MEMORY_SCOPE_AGENT);
}
__device__ __forceinline__ float bflo(unsigned u) { return __uint_as_float(u << 16); }
__device__ __forceinline__ float bfhi(unsigned u) { return __uint_as_float(u & 0xffff0000u); }
__device__ __forceinline__ unsigned packbf(float lo, float hi) {
  bf16 a = (bf16)lo, b = (bf16)hi;
  unsigned short ua = __builtin_bit_cast(unsigned short, a);
  unsigned short ub = __builtin_bit_cast(unsigned short, b);
  return (unsigned)ua | ((unsigned)ub << 16);
}

// ---------------------------------------------------------------------------
// Prep: cast weights, gather embeddings, zero control area.
// ctl: [0..31] step flags, ONE 128B line (4B stride); [1024] predec counter;
// [1056+32*t] hcat counters (t<48, target NBLK_ATT).
// ---------------------------------------------------------------------------
__global__ void prep_kernel(
    const int* __restrict__ kws, const int* __restrict__ poem,
    const float* __restrict__ emb,
    const float* __restrict__ eWih, const float* __restrict__ eWhh,
    const float* __restrict__ dWih, const float* __restrict__ dWhh,
    const float* __restrict__ outW,
    bf16* __restrict__ WihE, bf16* __restrict__ WhhE,
    bf16* __restrict__ WihD, bf16* __restrict__ WhhD,
    bf16* __restrict__ outWb,
    bf16* __restrict__ Xenc, bf16* __restrict__ Xdec,
    unsigned* __restrict__ ctl)
{
  if (blockIdx.x == 0)
    for (int i = threadIdx.x; i < 8192; i += blockDim.x) ctl[i] = 0u;
  const long SW = 1048576;       // 2048*512
  const long SOWP = 10354688;    // 10112*1024 (padded)
  const long SXE = 524288;       // 1024*512
  const long SXD = 3145728;      // 6144*512
  const long total = 4 * SW + SOWP + SXE + SXD;
  for (long i = blockIdx.x * (long)blockDim.x + threadIdx.x; i < total;
       i += (long)gridDim.x * blockDim.x) {
    long j = i;
    if (j < SW) { WihE[j] = (bf16)eWih[j]; continue; } j -= SW;
    if (j < SW) { WhhE[j] = (bf16)eWhh[j]; continue; } j -= SW;
    if (j < SW) { WihD[j] = (bf16)dWih[j]; continue; } j -= SW;
    if (j < SW) { WhhD[j] = (bf16)dWhh[j]; continue; } j -= SW;
    if (j < SOWP) {
      long r = j >> 10;
      outWb[j] = (r < 10000) ? (bf16)outW[j] : (bf16)0.f;
      continue;
    } j -= SOWP;
    if (j < SXE) {
      int e = (int)(j & 511); int b = (int)((j >> 9) & 127); int l = (int)(j >> 16);
      int tok = kws[b * L_ + l];
      Xenc[j] = (bf16)emb[(long)tok * 512 + e];
      continue;
    } j -= SXE;
    {
      int e = (int)(j & 511); int b = (int)((j >> 9) & 127); int t = (int)(j >> 16);
      int tok = poem[b * T_ + t];
      Xdec[j] = (bf16)emb[(long)tok * 512 + e];
    }
  }
}

// ---------------------------------------------------------------------------
// preEnc pre-gate GEMM (separate launch): [t][2048][128] bf16 transposed store.
// ---------------------------------------------------------------------------
__global__ __launch_bounds__(256) void gemm_pre_kernel(
    const bf16* __restrict__ A, const bf16* __restrict__ Bm,
    const float* __restrict__ bias, bf16* __restrict__ outp,
    int M, int N, int K, int MT)
{
  __shared__ bf16 As[128 * 32];
  __shared__ bf16 Bs[128 * 32];
  const int tid = threadIdx.x, lane = tid & 63, wid = tid >> 6;
  const int nwg = gridDim.x;
  int bid = blockIdx.x;
  int swz = ((nwg & 7) == 0) ? ((bid & 7) * (nwg >> 3) + (bid >> 3)) : bid;
  const int tm = swz % MT, tn = swz / MT;
  const int m0 = tm * 128, n0 = tn * 128;
  const int wm = (wid >> 1) * 64, wn = (wid & 1) * 64;
  const int fr = lane & 15, ku = lane >> 4;

  f32x4 acc[4][4];
  #pragma unroll
  for (int mi = 0; mi < 4; ++mi)
    #pragma unroll
    for (int ni = 0; ni < 4; ++ni) {
      acc[mi][ni][0] = 0.f; acc[mi][ni][1] = 0.f;
      acc[mi][ni][2] = 0.f; acc[mi][ni][3] = 0.f;
    }

  for (int kt = 0; kt < K; kt += 32) {
    #pragma unroll
    for (int j = 0; j < 2; ++j) {
      int i0 = j * 256 + wid * 64;
      int i = i0 + lane;
      int r = i >> 2, ub = i & 3;
      gl_lds16(A + (size_t)(m0 + r) * K + kt + ub * 8, As + (size_t)i0 * 8);
      gl_lds16(Bm + (size_t)(n0 + r) * K + kt + ub * 8, Bs + (size_t)i0 * 8);
    }
    __syncthreads();
    bf16x8 af[4], bfr[4];
    #pragma unroll
    for (int mi = 0; mi < 4; ++mi)
      af[mi] = *(const bf16x8*)(As + (size_t)(wm + mi * 16 + fr) * 32 + ku * 8);
    #pragma unroll
    for (int ni = 0; ni < 4; ++ni)
      bfr[ni] = *(const bf16x8*)(Bs + (size_t)(wn + ni * 16 + fr) * 32 + ku * 8);
    #pragma unroll
    for (int mi = 0; mi < 4; ++mi)
      #pragma unroll
      for (int ni = 0; ni < 4; ++ni)
        acc[mi][ni] = __builtin_amdgcn_mfma_f32_16x16x32_bf16(af[mi], bfr[ni], acc[mi][ni], 0, 0, 0);
    __syncthreads();
  }

  const int fq = (lane >> 4) * 4;
  #pragma unroll
  for (int mi = 0; mi < 4; ++mi) {
    #pragma unroll
    for (int ni = 0; ni < 4; ++ni) {
      #pragma unroll
      for (int j = 0; j < 4; ++j) {
        int r = m0 + wm + mi * 16 + fq + j;
        int cix = n0 + wn + ni * 16 + fr;
        outp[((size_t)(r >> 7) * 2048 + cix) * 128 + (r & 127)] = (bf16)(acc[mi][ni][j] + bias[cix]);
      }
    }
  }
}

// ---------------------------------------------------------------------------
// Fused persistent kernel:
//   blocks  0..31  recurrence (pure: wait -> gemm -> store -> signal)
//   blocks 32..47  attention workers (8 batches each, hsEnc in regs)
//   blocks 48..239 GEMM workers: preDec pre-gates, then n-band projection
// All step flags live in ONE 128B line -> 1 transaction per poll round.
// ---------------------------------------------------------------------------
__global__ __launch_bounds__(256, 1) void fused_kernel(
    const bf16* __restrict__ preEncT, bf16* __restrict__ preDecT,
    const bf16* __restrict__ WhhE, const bf16* __restrict__ WhhD,
    const int* __restrict__ kwl,
    bf16* __restrict__ hS, bf16* __restrict__ h0b,
    bf16* __restrict__ hsEnc, bf16* __restrict__ Hcat,
    const bf16* __restrict__ Xdec, const bf16* __restrict__ WihD,
    const float* __restrict__ db, const bf16* __restrict__ outWb,
    const float* __restrict__ outb, float* __restrict__ out,
    unsigned* __restrict__ ctl)
{
  __shared__ __align__(16) char pool[131072];
  const int tid = threadIdx.x, lane = tid & 63, wid = tid >> 6;
  unsigned* flg = ctl;     // flags at 4B stride, one 128B line

  auto waitflags = [&](unsigned step) {
    if (tid < 64) {
      for (;;) {
        unsigned v = (tid < NBLK_REC) ? aload32(flg + tid) : step;
        if (__all((int)(v >= step))) break;
      }
    }
    __syncthreads();
  };

  if (blockIdx.x < NBLK_REC) {
    // ===================== recurrent blocks =====================
    bf16* Bs = (bf16*)pool;             // 64 KB persistent Whh slice
    bf16* As = (bf16*)(pool + 65536);   // 64 KB h chunk / bounce
    const int blk = blockIdx.x, n0 = blk * 16;
    const int fr = lane & 15, fq = (lane >> 4) * 4, ku = lane >> 4;
    const int axor = fr & 7;
    const int arow0 = wid * 32 + fr, arow1 = wid * 32 + 16 + fr;
    const int row0 = wid * 32 + fq, row1 = wid * 32 + 16 + fq;
    const int brow = tid >> 1, bhalf = tid & 1;
    const int blen = kwl[brow];
    int lenr[2][4];
    #pragma unroll
    for (int j = 0; j < 4; ++j) { lenr[0][j] = kwl[row0 + j]; lenr[1][j] = kwl[row1 + j]; }

    auto signal = [&](unsigned step) {
      asm volatile("s_waitcnt vmcnt(0)" ::: "memory");
      __syncthreads();
      if (tid == 0)
        __hip_atomic_store(flg + blk, step, __ATOMIC_RELAXED, __HIP_MEMORY_SCOPE_AGENT);
    };

    auto loadB = [&](const bf16* W) {
      #pragma unroll
      for (int j = 0; j < 16; ++j) {
        int i = j * 256 + tid;
        int r = i >> 6, u = i & 63;
        int p = u ^ (r & 7);
        bf16x8 v = *(const bf16x8*)(W + (size_t)((r >> 4) * 512 + n0 + (r & 15)) * 512 + u * 8);
        *(bf16x8*)(Bs + (size_t)r * 512 + p * 8) = v;
      }
    };

    f32x4 acc[2][4];
    auto zacc = [&]() {
      #pragma unroll
      for (int mi = 0; mi < 2; ++mi)
        #pragma unroll
        for (int g = 0; g < 4; ++g) {
          acc[mi][g][0] = 0.f; acc[mi][g][1] = 0.f;
          acc[mi][g][2] = 0.f; acc[mi][g][3] = 0.f;
        }
    };

    auto gemm_full = [&](const bf16* h_in) {
      #pragma unroll
      for (int ch = 0; ch < 2; ++ch) {
        f32x4 tv[16];
        #pragma unroll
        for (int j = 0; j < 16; ++j) {
          int i = j * 256 + tid;
          int r = i >> 5, up = i & 31;
          const bf16* ga = h_in + (size_t)r * 512 + ch * 256 + up * 8;
          asm volatile("global_load_dwordx4 %0, %1, off sc0 sc1"
                       : "=v"(tv[j]) : "v"(ga) : "memory");
        }
        asm volatile("s_waitcnt vmcnt(0)" ::: "memory");
        __builtin_amdgcn_sched_barrier(0);
        #pragma unroll
        for (int j = 0; j < 16; ++j) {
          int i = j * 256 + tid;
          int r = i >> 5, up = i & 31;
          int s = up ^ (r & 7);
          *(f32x4*)(As + ((size_t)r * 32 + s) * 8) = tv[j];
        }
        __syncthreads();
        #pragma unroll
        for (int kt = 0; kt < 8; ++kt) {
          int cA = (kt * 4 + ku) ^ axor;
          int cB = ((ch * 8 + kt) * 4 + ku) ^ axor;
          bf16x8 af0 = *(const bf16x8*)(As + (size_t)arow0 * 256 + cA * 8);
          bf16x8 af1 = *(const bf16x8*)(As + (size_t)arow1 * 256 + cA * 8);
          #pragma unroll
          for (int g = 0; g < 4; ++g) {
            bf16x8 bv = *(const bf16x8*)(Bs + (size_t)(g * 16 + fr) * 512 + cB * 8);
            acc[0][g] = __builtin_amdgcn_mfma_f32_16x16x32_bf16(af0, bv, acc[0][g], 0, 0, 0);
            acc[1][g] = __builtin_amdgcn_mfma_f32_16x16x32_bf16(af1, bv, acc[1][g], 0, 0, 0);
          }
        }
        __syncthreads();
      }
    };

    float cr[2][4] = {{0.f,0.f,0.f,0.f},{0.f,0.f,0.f,0.f}};
    float c0r[2][4] = {{0.f,0.f,0.f,0.f},{0.f,0.f,0.f,0.f}};
    bf16 hout[2][4];
    bf16x4 gv[2][4];

    auto prefg = [&](const bf16* preT) {
      #pragma unroll
      for (int mi = 0; mi < 2; ++mi) {
        int rbase = mi ? row1 : row0;
        int hcol = n0 + fr;
        #pragma unroll
        for (int g = 0; g < 4; ++g)
          gv[mi][g] = *(const bf16x4*)(preT + ((size_t)(g * 512 + hcol)) * 128 + rbase);
      }
    };

    auto pointwise = [&]() {
      #pragma unroll
      for (int mi = 0; mi < 2; ++mi) {
        #pragma unroll
        for (int j = 0; j < 4; ++j) {
          float gi = acc[mi][0][j] + (float)gv[mi][0][j];
          float gf = acc[mi][1][j] + (float)gv[mi][1][j];
          float gg = acc[mi][2][j] + (float)gv[mi][2][j];
          float go = acc[mi][3][j] + (float)gv[mi][3][j];
          float cn = sigf(gf) * cr[mi][j] + sigf(gi) * tanhf(gg);
          float hn = sigf(go) * tanhf(cn);
          cr[mi][j] = cn;
          hout[mi][j] = (bf16)hn;
        }
      }
    };

    auto bounce_store = [&](bf16* hdst, bf16* hsdst, int t, int is_enc) {
      #pragma unroll
      for (int mi = 0; mi < 2; ++mi) {
        int rbase = mi ? row1 : row0;
        #pragma unroll
        for (int j = 0; j < 4; ++j)
          As[(size_t)(rbase + j) * 16 + fr] = hout[mi][j];
      }
      __syncthreads();
      f32x4 v = *(f32x4*)(As + (size_t)brow * 16 + bhalf * 8);
      size_t off = (size_t)brow * 512 + n0 + bhalf * 8;
      {
        bf16* d = hdst + off;
        asm volatile("global_store_dwordx4 %0, %1, off sc0 sc1" :: "v"(d), "v"(v) : "memory");
      }
      if (is_enc) {
        f32x4 z; z[0] = 0.f; z[1] = 0.f; z[2] = 0.f; z[3] = 0.f;
        f32x4 vm = (t < blen) ? v : z;
        bf16* dm = hsdst + off;
        asm volatile("global_store_dwordx4 %0, %1, off sc0 sc1" :: "v"(dm), "v"(vm) : "memory");
        if (t == blen - 1) {
          bf16* dh = h0b + off;
          asm volatile("global_store_dwordx4 %0, %1, off sc0 sc1" :: "v"(dh), "v"(v) : "memory");
        }
      }
    };

    // ---------------- encoder ----------------
    loadB(WhhE);
    __syncthreads();
    for (int t = 0; t < 8; ++t) {
      prefg(preEncT + (size_t)t * 262144);
      zacc();
      if (t > 0) {
        waitflags((unsigned)t);
        gemm_full(hS + (size_t)(t - 1) * 65536);
      }
      pointwise();
      #pragma unroll
      for (int mi = 0; mi < 2; ++mi)
        #pragma unroll
        for (int j = 0; j < 4; ++j)
          if (t == lenr[mi][j] - 1) c0r[mi][j] = cr[mi][j];
      bounce_store(hS + (size_t)t * 65536, hsEnc + (size_t)t * 65536, t, 1);
      signal((unsigned)(t + 1));
    }

    // ---------------- phase switch ----------------
    __syncthreads();
    loadB(WhhD);
    __syncthreads();
    waitflags(8u);
    #pragma unroll
    for (int mi = 0; mi < 2; ++mi)
      #pragma unroll
      for (int j = 0; j < 4; ++j) cr[mi][j] = c0r[mi][j];
    if (tid == 0) {                         // preDec pre-gates complete?
      unsigned v; int it = 0;
      do {
        asm volatile("global_load_dword %0, %1, off sc0 sc1\ns_waitcnt vmcnt(0)"
                     : "=v"(v) : "v"(ctl + 1024) : "memory");
        if (v >= 768u) break;
        __builtin_amdgcn_s_sleep(4);
      } while (++it < (1 << 20));
    }
    __syncthreads();

    // ---------------- decoder (no attention here) ----------------
    for (int t = 0; t < 48; ++t) {
      prefg(preDecT + (size_t)t * 262144);
      zacc();
      const bf16* hin = (t == 0) ? (const bf16*)h0b
                                 : (const bf16*)(hS + (size_t)(8 + t - 1) * 65536);
      waitflags((unsigned)(8 + t));
      gemm_full(hin);
      pointwise();
      bounce_store(hS + (size_t)(8 + t) * 65536, nullptr, t, 0);
      signal((unsigned)(9 + t));
    }

  } else if (blockIdx.x < NBLK_REC + NBLK_ATT) {
    // ===================== attention workers =====================
    const int a = blockIdx.x - NBLK_REC;   // 0..15
    const int b0 = a * 8 + wid * 2;        // wave handles batches b0, b0+1
    const int lenb0 = kwl[b0], lenb1 = kwl[b0 + 1];

    waitflags(8u);                          // encoder done
    unsigned hsr[2][8][4];
    #pragma unroll
    for (int bb = 0; bb < 2; ++bb)
      #pragma unroll
      for (int l = 0; l < 8; ++l)
        #pragma unroll
        for (int e = 0; e < 4; ++e) {
          const bf16* p = hsEnc + (size_t)l * 65536 + (size_t)(b0 + bb) * 512 + lane * 2 + 128 * e;
          asm volatile("global_load_dword %0, %1, off sc0 sc1" : "=v"(hsr[bb][l][e]) : "v"(p) : "memory");
        }
    asm volatile("s_waitcnt vmcnt(0)" ::: "memory");
    __builtin_amdgcn_sched_barrier(0);

    for (int tp = 0; tp < 48; ++tp) {
      waitflags((unsigned)(9 + tp));        // hS[8+tp] ready
      const bf16* hin = hS + (size_t)(8 + tp) * 65536;
      unsigned hatt[2][4];
      #pragma unroll
      for (int bb = 0; bb < 2; ++bb)
        #pragma unroll
        for (int e = 0; e < 4; ++e) {
          const bf16* p = hin + (size_t)(b0 + bb) * 512 + lane * 2 + 128 * e;
          asm volatile("global_load_dword %0, %1, off sc0 sc1" : "=v"(hatt[bb][e]) : "v"(p) : "memory");
        }
      asm volatile("s_waitcnt vmcnt(0)" ::: "memory");
      __builtin_amdgcn_sched_barrier(0);
      #pragma unroll
      for (int bb = 0; bb < 2; ++bb) {
        const int b = b0 + bb;
        const int len = bb ? lenb1 : lenb0;
        float sc[8];
        #pragma unroll
        for (int l = 0; l < 8; ++l) {
          float p = 0.f;
          #pragma unroll
          for (int e = 0; e < 4; ++e)
            p += bflo(hatt[bb][e]) * bflo(hsr[bb][l][e]) + bfhi(hatt[bb][e]) * bfhi(hsr[bb][l][e]);
          #pragma unroll
          for (int off = 32; off; off >>= 1) p += __shfl_xor(p, off);
          sc[l] = p;
        }
        float m = -1e30f;
        #pragma unroll
        for (int l = 0; l < 8; ++l) m = fmaxf(m, (l < len) ? sc[l] : -1e30f);
        float wgt[8]; float den = 0.f;
        #pragma unroll
        for (int l = 0; l < 8; ++l) { wgt[l] = (l < len) ? expf(sc[l] - m) : 0.f; den += wgt[l]; }
        float inv = 1.f / den;
        bf16* dst = Hcat + ((size_t)tp * 128 + b) * 1024;
        #pragma unroll
        for (int e = 0; e < 4; ++e) {
          float clo = 0.f, chi = 0.f;
          #pragma unroll
          for (int l = 0; l < 8; ++l) {
            clo += wgt[l] * bflo(hsr[bb][l][e]);
            chi += wgt[l] * bfhi(hsr[bb][l][e]);
          }
          unsigned cw = packbf(clo * inv, chi * inv);
          unsigned* d1 = (unsigned*)(dst + 512 + lane * 2 + 128 * e);
          unsigned* d0 = (unsigned*)(dst + lane * 2 + 128 * e);
          asm volatile("global_store_dword %0, %1, off sc0 sc1" :: "v"(d1), "v"(cw) : "memory");
          asm volatile("global_store_dword %0, %1, off sc0 sc1" :: "v"(d0), "v"(hatt[bb][e]) : "memory");
        }
      }
      asm volatile("s_waitcnt vmcnt(0)" ::: "memory");
      __syncthreads();
      if (tid == 0)
        __hip_atomic_fetch_add(ctl + 1056 + tp * 32, 1u, __ATOMIC_RELAXED, __HIP_MEMORY_SCOPE_AGENT);
      __syncthreads();
    }

  } else {
    // ===================== GEMM workers =====================
    const int w2 = blockIdx.x - NBLK_REC - NBLK_ATT;   // 0..191
    const int fr = lane & 15, ku = lane >> 4;
    const int fq = (lane >> 4) * 4;
    bf16* AsW = (bf16*)pool;             // 8 KB
    bf16* BsW = (bf16*)(pool + 8192);    // 8 KB
    bf16* Tb  = (bf16*)(pool + 16384);   // 32 KB transpose bounce (phase 1)
    const int wm = (wid >> 1) * 64, wn = (wid & 1) * 64;

    auto wait_ge = [&](unsigned* p, unsigned target) {
      if (tid == 0) {
        unsigned v; int it = 0;
        do {
          asm volatile("global_load_dword %0, %1, off sc0 sc1\ns_waitcnt vmcnt(0)"
                       : "=v"(v) : "v"(p) : "memory");
          if (v >= target) break;
          __builtin_amdgcn_s_sleep(8);
        } while (++it < (1 << 20));
      }
      __syncthreads();
    };

    // ---- phase 1: preDec pre-gate tiles (768 tiles over 192 workers) ----
    for (int i = w2; i < 768; i += NWG) {
      int t = i >> 4, tn = i & 15;
      int m0 = t * 128, n0 = tn * 128;
      f32x4 acc[4][4];
      #pragma unroll
      for (int mi = 0; mi < 4; ++mi)
        #pragma unroll
        for (int ni = 0; ni < 4; ++ni) {
          acc[mi][ni][0] = 0.f; acc[mi][ni][1] = 0.f;
          acc[mi][ni][2] = 0.f; acc[mi][ni][3] = 0.f;
        }
      for (int kt = 0; kt < 512; kt += 32) {
        #pragma unroll
        for (int j = 0; j < 2; ++j) {
          int i0 = j * 256 + wid * 64;
          int ii = i0 + lane;
          int r = ii >> 2, q = ii & 3;
          gl_lds16(Xdec + (size_t)(m0 + r) * 512 + kt + q * 8, AsW + (size_t)i0 * 8);
          gl_lds16(WihD + (size_t)(n0 + r) * 512 + kt + q * 8, BsW + (size_t)i0 * 8);
        }
        __syncthreads();
        bf16x8 af[4], bfr[4];
        #pragma unroll
        for (int mi = 0; mi < 4; ++mi)
          af[mi] = *(const bf16x8*)(AsW + (size_t)(wm + mi * 16 + fr) * 32 + ku * 8);
        #pragma unroll
        for (int ni = 0; ni < 4; ++ni)
          bfr[ni] = *(const bf16x8*)(BsW + (size_t)(wn + ni * 16 + fr) * 32 + ku * 8);
        #pragma unroll
        for (int mi = 0; mi < 4; ++mi)
          #pragma unroll
          for (int ni = 0; ni < 4; ++ni)
            acc[mi][ni] = __builtin_amdgcn_mfma_f32_16x16x32_bf16(af[mi], bfr[ni], acc[mi][ni], 0, 0, 0);
        __syncthreads();
      }
      #pragma unroll
      for (int mi = 0; mi < 4; ++mi)
        #pragma unroll
        for (int ni = 0; ni < 4; ++ni) {
          int cl = wn + ni * 16 + fr;
          float bias = db[n0 + cl];
          #pragma unroll
          for (int j = 0; j < 4; ++j)
            Tb[(size_t)cl * 128 + (wm + mi * 16 + fq + j)] = (bf16)(acc[mi][ni][j] + bias);
        }
      __syncthreads();
      #pragma unroll
      for (int rep = 0; rep < 8; ++rep) {
        int u = rep * 256 + tid;
        int cl = u >> 4, cb = u & 15;
        f32x4 v = *(f32x4*)(Tb + (size_t)cl * 128 + cb * 8);
        bf16* dst = preDecT + ((size_t)t * 2048 + n0 + cl) * 128 + cb * 8;
        asm volatile("global_store_dwordx4 %0, %1, off sc0 sc1" :: "v"(dst), "v"(v) : "memory");
      }
      asm volatile("s_waitcnt vmcnt(0)" ::: "memory");
      __syncthreads();
      if (tid == 0)
        __hip_atomic_fetch_add(ctl + 1024, 1u, __ATOMIC_RELAXED, __HIP_MEMORY_SCOPE_AGENT);
      __syncthreads();
    }

    // ---- phase 2: n-band output projection ----
    // worker w2<158: n-band = w2>>1, t parity = w2&1 -> 24 tiles, B L2-resident.
    if (w2 >= 158) return;
    const int n = w2 >> 1, tpar = w2 & 1;
    const int n0 = n * 128;
    for (int t = tpar; t < 48; t += 2) {
      wait_ge(ctl + 1056 + t * 32, (unsigned)NBLK_ATT);
      const bf16* Abase = Hcat + (size_t)t * 131072;
      f32x4 acc[4][4];
      #pragma unroll
      for (int mi = 0; mi < 4; ++mi)
        #pragma unroll
        for (int ni = 0; ni < 4; ++ni) {
          acc[mi][ni][0] = 0.f; acc[mi][ni][1] = 0.f;
          acc[mi][ni][2] = 0.f; acc[mi][ni][3] = 0.f;
        }
      for (int kt = 0; kt < 1024; kt += 32) {
        #pragma unroll
        for (int j = 0; j < 2; ++j) {
          int i0 = j * 256 + wid * 64;
          int ii = i0 + lane;
          int r = ii >> 2, q = ii & 3;
          gl_lds16(Abase + (size_t)r * 1024 + kt + q * 8, AsW + (size_t)i0 * 8);
          gl_lds16(outWb + (size_t)(n0 + r) * 1024 + kt + q * 8, BsW + (size_t)i0 * 8);
        }
        __syncthreads();
        bf16x8 af[4], bfr[4];
        #pragma unroll
        for (int mi = 0; mi < 4; ++mi)
          af[mi] = *(const bf16x8*)(AsW + (size_t)(wm + mi * 16 + fr) * 32 + ku * 8);
        #pragma unroll
        for (int ni = 0; ni < 4; ++ni)
          bfr[ni] = *(const bf16x8*)(BsW + (size_t)(wn + ni * 16 + fr) * 32 + ku * 8);
        #pragma unroll
        for (int mi = 0; mi < 4; ++mi)
          #pragma unroll
          for (int ni = 0; ni < 4; ++ni)
            acc[mi][ni] = __builtin_amdgcn_mfma_f32_16x16x32_bf16(af[mi], bfr[ni], acc[mi][ni], 0, 0, 0);
        __syncthreads();
      }
      #pragma unroll
      for (int mi = 0; mi < 4; ++mi) {
        #pragma unroll
        for (int ni = 0; ni < 4; ++ni) {
          int cix = n0 + wn + ni * 16 + fr;
          if (cix < V_) {
            float bias = outb[cix];
            #pragma unroll
            for (int j = 0; j < 4; ++j) {
              int b = wm + mi * 16 + fq + j;
              out[(size_t)b * (T_ * V_) + (size_t)t * V_ + cix] = acc[mi][ni][j] + bias;
            }
          }
        }
      }
    }
  }
}

// ---------------------------------------------------------------------------
extern "C" void kernel_launch(void* const* d_in, const int* in_sizes, int n_in,
                              void* d_out, int out_size, void* d_ws, size_t ws_size,
                              hipStream_t stream)
{
  const int* kws  = (const int*)d_in[0];
  const int* poem = (const int*)d_in[1];
  const int* kwl  = (const int*)d_in[2];
  const float* emb  = (const float*)d_in[3];
  const float* eWih = (const float*)d_in[4];
  const float* eWhh = (const float*)d_in[5];
  const float* eb   = (const float*)d_in[6];
  const float* dWih = (const float*)d_in[7];
  const float* dWhh = (const float*)d_in[8];
  const float* db   = (const float*)d_in[9];
  const float* outW = (const float*)d_in[10];
  const float* outb = (const float*)d_in[11];
  float* out = (float*)d_out;

  char* base = (char*)d_ws;
  size_t o = 0;
  auto take = [&](size_t bytes) -> char* {
    char* r = base + o;
    o += (bytes + 255) & ~(size_t)255;
    return r;
  };
  bf16* WihE  = (bf16*)take(2048 * 512 * 2);
  bf16* WhhE  = (bf16*)take(2048 * 512 * 2);
  bf16* WihD  = (bf16*)take(2048 * 512 * 2);
  bf16* WhhD  = (bf16*)take(2048 * 512 * 2);
  bf16* outWb = (bf16*)take((size_t)10112 * 1024 * 2);
  bf16* Xenc  = (bf16*)take(1024 * 512 * 2);
  bf16* Xdec  = (bf16*)take((size_t)6144 * 512 * 2);
  bf16* preEncT = (bf16*)take((size_t)8 * 2048 * 128 * 2);
  bf16* preDecT = (bf16*)take((size_t)48 * 2048 * 128 * 2);
  bf16* Hcat   = (bf16*)take((size_t)6144 * 1024 * 2);
  bf16* hS     = (bf16*)take((size_t)56 * 65536 * 2);
  bf16* hsEnc  = (bf16*)take((size_t)8 * 128 * 512 * 2);
  bf16* h0b    = (bf16*)take(128 * 512 * 2);
  unsigned* ctl = (unsigned*)take(32768);

  prep_kernel<<<4096, 256, 0, stream>>>(kws, poem, emb, eWih, eWhh, dWih, dWhh, outW,
                                        WihE, WhhE, WihD, WhhD, outWb, Xenc, Xdec, ctl);

  // encoder pre-gates (needed at recurrence step 0)
  gemm_pre_kernel<<<128, 256, 0, stream>>>(Xenc, WihE, eb, preEncT, 1024, 2048, 512, 8);

  // fused: recurrence + attention workers + preDec pre-gates + projection
  fused_kernel<<<NBLK_TOT, 256, 0, stream>>>(preEncT, preDecT, WhhE, WhhD, kwl,
                                             hS, h0b, hsEnc, Hcat,
                                             Xdec, WihD, db, outWb, outb, out, ctl);
}

// Round 13
// 634.432 us; speedup vs baseline: 1.0382x; 1.0382x over previous
//
#include <hip/hip_runtime.h>
#include <hip/hip_bf16.h>

typedef __bf16 bf16;
typedef __attribute__((ext_vector_type(8))) __bf16 bf16x8;
typedef __attribute__((ext_vector_type(4))) __bf16 bf16x4;
typedef __attribute__((ext_vector_type(4))) float f32x4;

#define B_ 128
#define L_ 8
#define T_ 48
#define V_ 10000
#define NBLK_REC 32
#define NBLK_ATT 16
#define NBLK_TOT 240
#define NWG 192            // GEMM worker blocks (blockIdx 48..239)

__device__ __forceinline__ float sigf(float x) { return 1.f / (1.f + expf(-x)); }

__device__ __forceinline__ void gl_lds16(const bf16* g, bf16* l) {
  __builtin_amdgcn_global_load_lds(
      (const __attribute__((address_space(1))) unsigned int*)g,
      (__attribute__((address_space(3))) unsigned int*)l, 16, 0, 0);
}

__device__ __forceinline__ unsigned aload32(const void* p) {
  return __hip_atomic_load((unsigned*)p, __ATOMIC_RELAXED, __HIP_MEMORY_SCOPE_AGENT);
}
__device__ __forceinline__ void astore64(void* p, unsigned long long v) {
  __hip_atomic_store((unsigned long long*)p, v, __ATOMIC_RELAXED, __HIP_MEMORY_SCOPE_AGENT);
}
__device__ __forceinline__ float bflo(unsigned u) { return __uint_as_float(u << 16); }
__device__ __forceinline__ float bfhi(unsigned u) { return __uint_as_float(u & 0xffff0000u); }
__device__ __forceinline__ unsigned packbf(float lo, float hi) {
  bf16 a = (bf16)lo, b = (bf16)hi;
  unsigned short ua = __builtin_bit_cast(unsigned short, a);
  unsigned short ub = __builtin_bit_cast(unsigned short, b);
  return (unsigned)ua | ((unsigned)ub << 16);
}

// ---------------------------------------------------------------------------
// Prep: cast weights, gather embeddings, zero control area.
// ctl: [blk*32] step flags (blk<32); [1024] predec counter; [1056+32*t] hcat
// counters (t<48, target NBLK_ATT).
// ---------------------------------------------------------------------------
__global__ void prep_kernel(
    const int* __restrict__ kws, const int* __restrict__ poem,
    const float* __restrict__ emb,
    const float* __restrict__ eWih, const float* __restrict__ eWhh,
    const float* __restrict__ dWih, const float* __restrict__ dWhh,
    const float* __restrict__ outW,
    bf16* __restrict__ WihE, bf16* __restrict__ WhhE,
    bf16* __restrict__ WihD, bf16* __restrict__ WhhD,
    bf16* __restrict__ outWb,
    bf16* __restrict__ Xenc, bf16* __restrict__ Xdec,
    unsigned* __restrict__ ctl)
{
  if (blockIdx.x == 0)
    for (int i = threadIdx.x; i < 8192; i += blockDim.x) ctl[i] = 0u;
  const long SW = 1048576;       // 2048*512
  const long SOWP = 10354688;    // 10112*1024 (padded)
  const long SXE = 524288;       // 1024*512
  const long SXD = 3145728;      // 6144*512
  const long total = 4 * SW + SOWP + SXE + SXD;
  for (long i = blockIdx.x * (long)blockDim.x + threadIdx.x; i < total;
       i += (long)gridDim.x * blockDim.x) {
    long j = i;
    if (j < SW) { WihE[j] = (bf16)eWih[j]; continue; } j -= SW;
    if (j < SW) { WhhE[j] = (bf16)eWhh[j]; continue; } j -= SW;
    if (j < SW) { WihD[j] = (bf16)dWih[j]; continue; } j -= SW;
    if (j < SW) { WhhD[j] = (bf16)dWhh[j]; continue; } j -= SW;
    if (j < SOWP) {
      long r = j >> 10;
      outWb[j] = (r < 10000) ? (bf16)outW[j] : (bf16)0.f;
      continue;
    } j -= SOWP;
    if (j < SXE) {
      int e = (int)(j & 511); int b = (int)((j >> 9) & 127); int l = (int)(j >> 16);
      int tok = kws[b * L_ + l];
      Xenc[j] = (bf16)emb[(long)tok * 512 + e];
      continue;
    } j -= SXE;
    {
      int e = (int)(j & 511); int b = (int)((j >> 9) & 127); int t = (int)(j >> 16);
      int tok = poem[b * T_ + t];
      Xdec[j] = (bf16)emb[(long)tok * 512 + e];
    }
  }
}

// ---------------------------------------------------------------------------
// preEnc pre-gate GEMM (separate launch): [t][2048][128] bf16 transposed store.
// ---------------------------------------------------------------------------
__global__ __launch_bounds__(256) void gemm_pre_kernel(
    const bf16* __restrict__ A, const bf16* __restrict__ Bm,
    const float* __restrict__ bias, bf16* __restrict__ outp,
    int M, int N, int K, int MT)
{
  __shared__ bf16 As[128 * 32];
  __shared__ bf16 Bs[128 * 32];
  const int tid = threadIdx.x, lane = tid & 63, wid = tid >> 6;
  const int nwg = gridDim.x;
  int bid = blockIdx.x;
  int swz = ((nwg & 7) == 0) ? ((bid & 7) * (nwg >> 3) + (bid >> 3)) : bid;
  const int tm = swz % MT, tn = swz / MT;
  const int m0 = tm * 128, n0 = tn * 128;
  const int wm = (wid >> 1) * 64, wn = (wid & 1) * 64;
  const int fr = lane & 15, ku = lane >> 4;

  f32x4 acc[4][4];
  #pragma unroll
  for (int mi = 0; mi < 4; ++mi)
    #pragma unroll
    for (int ni = 0; ni < 4; ++ni) {
      acc[mi][ni][0] = 0.f; acc[mi][ni][1] = 0.f;
      acc[mi][ni][2] = 0.f; acc[mi][ni][3] = 0.f;
    }

  for (int kt = 0; kt < K; kt += 32) {
    #pragma unroll
    for (int j = 0; j < 2; ++j) {
      int i0 = j * 256 + wid * 64;
      int i = i0 + lane;
      int r = i >> 2, ub = i & 3;
      gl_lds16(A + (size_t)(m0 + r) * K + kt + ub * 8, As + (size_t)i0 * 8);
      gl_lds16(Bm + (size_t)(n0 + r) * K + kt + ub * 8, Bs + (size_t)i0 * 8);
    }
    __syncthreads();
    bf16x8 af[4], bfr[4];
    #pragma unroll
    for (int mi = 0; mi < 4; ++mi)
      af[mi] = *(const bf16x8*)(As + (size_t)(wm + mi * 16 + fr) * 32 + ku * 8);
    #pragma unroll
    for (int ni = 0; ni < 4; ++ni)
      bfr[ni] = *(const bf16x8*)(Bs + (size_t)(wn + ni * 16 + fr) * 32 + ku * 8);
    #pragma unroll
    for (int mi = 0; mi < 4; ++mi)
      #pragma unroll
      for (int ni = 0; ni < 4; ++ni)
        acc[mi][ni] = __builtin_amdgcn_mfma_f32_16x16x32_bf16(af[mi], bfr[ni], acc[mi][ni], 0, 0, 0);
    __syncthreads();
  }

  const int fq = (lane >> 4) * 4;
  #pragma unroll
  for (int mi = 0; mi < 4; ++mi) {
    #pragma unroll
    for (int ni = 0; ni < 4; ++ni) {
      #pragma unroll
      for (int j = 0; j < 4; ++j) {
        int r = m0 + wm + mi * 16 + fq + j;
        int cix = n0 + wn + ni * 16 + fr;
        outp[((size_t)(r >> 7) * 2048 + cix) * 128 + (r & 127)] = (bf16)(acc[mi][ni][j] + bias[cix]);
      }
    }
  }
}

// ---------------------------------------------------------------------------
// Fused persistent kernel:
//   blocks  0..31  recurrence (pure: wait -> gemm -> store -> signal)
//   blocks 32..47  attention workers (8 batches each, hsEnc in regs)
//   blocks 48..239 GEMM workers: preDec pre-gates, then n-band projection
//                  (fixed outWb panel per worker -> L2-resident B, LDS-staged)
// ---------------------------------------------------------------------------
__global__ __launch_bounds__(256, 1) void fused_kernel(
    const bf16* __restrict__ preEncT, bf16* __restrict__ preDecT,
    const bf16* __restrict__ WhhE, const bf16* __restrict__ WhhD,
    const int* __restrict__ kwl,
    bf16* __restrict__ hS, bf16* __restrict__ h0b,
    bf16* __restrict__ hsEnc, bf16* __restrict__ Hcat,
    const bf16* __restrict__ Xdec, const bf16* __restrict__ WihD,
    const float* __restrict__ db, const bf16* __restrict__ outWb,
    const float* __restrict__ outb, float* __restrict__ out,
    unsigned* __restrict__ ctl)
{
  __shared__ __align__(16) char pool[131072];
  const int tid = threadIdx.x, lane = tid & 63, wid = tid >> 6;
  unsigned* flg = ctl;

  auto waitflags = [&](unsigned step) {
    if (tid < 64) {
      int l = tid;
      for (;;) {
        unsigned v = (l < NBLK_REC) ? aload32(flg + l * 32) : step;
        if (__all((int)(v >= step))) break;
        __builtin_amdgcn_s_sleep(1);
      }
    }
    __syncthreads();
  };

  if (blockIdx.x < NBLK_REC) {
    // ===================== recurrent blocks =====================
    bf16* Bs = (bf16*)pool;             // 64 KB persistent Whh slice
    bf16* As = (bf16*)(pool + 65536);   // 64 KB h chunk / bounce
    const int blk = blockIdx.x, n0 = blk * 16;
    const int fr = lane & 15, fq = (lane >> 4) * 4, ku = lane >> 4;
    const int axor = fr & 7;
    const int arow0 = wid * 32 + fr, arow1 = wid * 32 + 16 + fr;
    const int row0 = wid * 32 + fq, row1 = wid * 32 + 16 + fq;
    const int brow = tid >> 1, bhalf = tid & 1;
    const int blen = kwl[brow];
    int lenr[2][4];
    #pragma unroll
    for (int j = 0; j < 4; ++j) { lenr[0][j] = kwl[row0 + j]; lenr[1][j] = kwl[row1 + j]; }

    auto signal = [&](unsigned step) {
      asm volatile("s_waitcnt vmcnt(0)" ::: "memory");
      __syncthreads();
      if (tid == 0)
        __hip_atomic_store(flg + blk * 32, step, __ATOMIC_RELAXED, __HIP_MEMORY_SCOPE_AGENT);
    };

    auto loadB = [&](const bf16* W) {
      #pragma unroll
      for (int j = 0; j < 16; ++j) {
        int i = j * 256 + tid;
        int r = i >> 6, u = i & 63;
        int p = u ^ (r & 7);
        bf16x8 v = *(const bf16x8*)(W + (size_t)((r >> 4) * 512 + n0 + (r & 15)) * 512 + u * 8);
        *(bf16x8*)(Bs + (size_t)r * 512 + p * 8) = v;
      }
    };

    f32x4 acc[2][4];
    auto zacc = [&]() {
      #pragma unroll
      for (int mi = 0; mi < 2; ++mi)
        #pragma unroll
        for (int g = 0; g < 4; ++g) {
          acc[mi][g][0] = 0.f; acc[mi][g][1] = 0.f;
          acc[mi][g][2] = 0.f; acc[mi][g][3] = 0.f;
        }
    };

    auto gemm_full = [&](const bf16* h_in) {
      #pragma unroll
      for (int ch = 0; ch < 2; ++ch) {
        f32x4 tv[16];
        #pragma unroll
        for (int j = 0; j < 16; ++j) {
          int i = j * 256 + tid;
          int r = i >> 5, up = i & 31;
          const bf16* ga = h_in + (size_t)r * 512 + ch * 256 + up * 8;
          asm volatile("global_load_dwordx4 %0, %1, off sc0 sc1"
                       : "=v"(tv[j]) : "v"(ga) : "memory");
        }
        asm volatile("s_waitcnt vmcnt(0)" ::: "memory");
        __builtin_amdgcn_sched_barrier(0);
        #pragma unroll
        for (int j = 0; j < 16; ++j) {
          int i = j * 256 + tid;
          int r = i >> 5, up = i & 31;
          int s = up ^ (r & 7);
          *(f32x4*)(As + ((size_t)r * 32 + s) * 8) = tv[j];
        }
        __syncthreads();
        #pragma unroll
        for (int kt = 0; kt < 8; ++kt) {
          int cA = (kt * 4 + ku) ^ axor;
          int cB = ((ch * 8 + kt) * 4 + ku) ^ axor;
          bf16x8 af0 = *(const bf16x8*)(As + (size_t)arow0 * 256 + cA * 8);
          bf16x8 af1 = *(const bf16x8*)(As + (size_t)arow1 * 256 + cA * 8);
          #pragma unroll
          for (int g = 0; g < 4; ++g) {
            bf16x8 bv = *(const bf16x8*)(Bs + (size_t)(g * 16 + fr) * 512 + cB * 8);
            acc[0][g] = __builtin_amdgcn_mfma_f32_16x16x32_bf16(af0, bv, acc[0][g], 0, 0, 0);
            acc[1][g] = __builtin_amdgcn_mfma_f32_16x16x32_bf16(af1, bv, acc[1][g], 0, 0, 0);
          }
        }
        __syncthreads();
      }
    };

    float cr[2][4] = {{0.f,0.f,0.f,0.f},{0.f,0.f,0.f,0.f}};
    float c0r[2][4] = {{0.f,0.f,0.f,0.f},{0.f,0.f,0.f,0.f}};
    bf16 hout[2][4];
    bf16x4 gv[2][4];

    auto prefg = [&](const bf16* preT) {
      #pragma unroll
      for (int mi = 0; mi < 2; ++mi) {
        int rbase = mi ? row1 : row0;
        int hcol = n0 + fr;
        #pragma unroll
        for (int g = 0; g < 4; ++g)
          gv[mi][g] = *(const bf16x4*)(preT + ((size_t)(g * 512 + hcol)) * 128 + rbase);
      }
    };

    auto pointwise = [&]() {
      #pragma unroll
      for (int mi = 0; mi < 2; ++mi) {
        #pragma unroll
        for (int j = 0; j < 4; ++j) {
          float gi = acc[mi][0][j] + (float)gv[mi][0][j];
          float gf = acc[mi][1][j] + (float)gv[mi][1][j];
          float gg = acc[mi][2][j] + (float)gv[mi][2][j];
          float go = acc[mi][3][j] + (float)gv[mi][3][j];
          float cn = sigf(gf) * cr[mi][j] + sigf(gi) * tanhf(gg);
          float hn = sigf(go) * tanhf(cn);
          cr[mi][j] = cn;
          hout[mi][j] = (bf16)hn;
        }
      }
    };

    auto bounce_store = [&](bf16* hdst, bf16* hsdst, int t, int is_enc) {
      #pragma unroll
      for (int mi = 0; mi < 2; ++mi) {
        int rbase = mi ? row1 : row0;
        #pragma unroll
        for (int j = 0; j < 4; ++j)
          As[(size_t)(rbase + j) * 16 + fr] = hout[mi][j];
      }
      __syncthreads();
      unsigned long long v0 = *(unsigned long long*)(As + (size_t)brow * 16 + bhalf * 8);
      unsigned long long v1 = *(unsigned long long*)(As + (size_t)brow * 16 + bhalf * 8 + 4);
      size_t off = (size_t)brow * 512 + n0 + bhalf * 8;
      astore64(hdst + off, v0);
      astore64(hdst + off + 4, v1);
      if (is_enc) {
        unsigned long long m0 = (t < blen) ? v0 : 0ull;
        unsigned long long m1 = (t < blen) ? v1 : 0ull;
        astore64(hsdst + off, m0);
        astore64(hsdst + off + 4, m1);
        if (t == blen - 1) {
          astore64(h0b + off, v0);
          astore64(h0b + off + 4, v1);
        }
      }
    };

    // ---------------- encoder ----------------
    loadB(WhhE);
    __syncthreads();
    for (int t = 0; t < 8; ++t) {
      prefg(preEncT + (size_t)t * 262144);
      zacc();
      if (t > 0) {
        waitflags((unsigned)t);
        gemm_full(hS + (size_t)(t - 1) * 65536);
      }
      pointwise();
      #pragma unroll
      for (int mi = 0; mi < 2; ++mi)
        #pragma unroll
        for (int j = 0; j < 4; ++j)
          if (t == lenr[mi][j] - 1) c0r[mi][j] = cr[mi][j];
      bounce_store(hS + (size_t)t * 65536, hsEnc + (size_t)t * 65536, t, 1);
      signal((unsigned)(t + 1));
    }

    // ---------------- phase switch ----------------
    __syncthreads();
    loadB(WhhD);
    __syncthreads();
    waitflags(8u);
    #pragma unroll
    for (int mi = 0; mi < 2; ++mi)
      #pragma unroll
      for (int j = 0; j < 4; ++j) cr[mi][j] = c0r[mi][j];
    if (tid == 0) {                         // preDec pre-gates complete?
      unsigned v; int it = 0;
      do {
        asm volatile("global_load_dword %0, %1, off sc0 sc1\ns_waitcnt vmcnt(0)"
                     : "=v"(v) : "v"(ctl + 1024) : "memory");
        if (v >= 768u) break;
        __builtin_amdgcn_s_sleep(4);
      } while (++it < (1 << 20));
    }
    __syncthreads();

    // ---------------- decoder (no attention here) ----------------
    for (int t = 0; t < 48; ++t) {
      prefg(preDecT + (size_t)t * 262144);
      zacc();
      const bf16* hin = (t == 0) ? (const bf16*)h0b
                                 : (const bf16*)(hS + (size_t)(8 + t - 1) * 65536);
      waitflags((unsigned)(8 + t));
      gemm_full(hin);
      pointwise();
      bounce_store(hS + (size_t)(8 + t) * 65536, nullptr, t, 0);
      signal((unsigned)(9 + t));
    }

  } else if (blockIdx.x < NBLK_REC + NBLK_ATT) {
    // ===================== attention workers =====================
    const int a = blockIdx.x - NBLK_REC;   // 0..15
    const int b0 = a * 8 + wid * 2;        // wave handles batches b0, b0+1
    const int lenb0 = kwl[b0], lenb1 = kwl[b0 + 1];

    waitflags(8u);                          // encoder done
    unsigned hsr[2][8][4];
    #pragma unroll
    for (int bb = 0; bb < 2; ++bb)
      #pragma unroll
      for (int l = 0; l < 8; ++l)
        #pragma unroll
        for (int e = 0; e < 4; ++e) {
          const bf16* p = hsEnc + (size_t)l * 65536 + (size_t)(b0 + bb) * 512 + lane * 2 + 128 * e;
          asm volatile("global_load_dword %0, %1, off sc0 sc1" : "=v"(hsr[bb][l][e]) : "v"(p) : "memory");
        }
    asm volatile("s_waitcnt vmcnt(0)" ::: "memory");
    __builtin_amdgcn_sched_barrier(0);

    for (int tp = 0; tp < 48; ++tp) {
      waitflags((unsigned)(9 + tp));        // hS[8+tp] ready
      const bf16* hin = hS + (size_t)(8 + tp) * 65536;
      unsigned hatt[2][4];
      #pragma unroll
      for (int bb = 0; bb < 2; ++bb)
        #pragma unroll
        for (int e = 0; e < 4; ++e) {
          const bf16* p = hin + (size_t)(b0 + bb) * 512 + lane * 2 + 128 * e;
          asm volatile("global_load_dword %0, %1, off sc0 sc1" : "=v"(hatt[bb][e]) : "v"(p) : "memory");
        }
      asm volatile("s_waitcnt vmcnt(0)" ::: "memory");
      __builtin_amdgcn_sched_barrier(0);
      #pragma unroll
      for (int bb = 0; bb < 2; ++bb) {
        const int b = b0 + bb;
        const int len = bb ? lenb1 : lenb0;
        float sc[8];
        #pragma unroll
        for (int l = 0; l < 8; ++l) {
          float p = 0.f;
          #pragma unroll
          for (int e = 0; e < 4; ++e)
            p += bflo(hatt[bb][e]) * bflo(hsr[bb][l][e]) + bfhi(hatt[bb][e]) * bfhi(hsr[bb][l][e]);
          #pragma unroll
          for (int off = 32; off; off >>= 1) p += __shfl_xor(p, off);
          sc[l] = p;
        }
        float m = -1e30f;
        #pragma unroll
        for (int l = 0; l < 8; ++l) m = fmaxf(m, (l < len) ? sc[l] : -1e30f);
        float wgt[8]; float den = 0.f;
        #pragma unroll
        for (int l = 0; l < 8; ++l) { wgt[l] = (l < len) ? expf(sc[l] - m) : 0.f; den += wgt[l]; }
        float inv = 1.f / den;
        bf16* dst = Hcat + ((size_t)tp * 128 + b) * 1024;
        #pragma unroll
        for (int e = 0; e < 4; ++e) {
          float clo = 0.f, chi = 0.f;
          #pragma unroll
          for (int l = 0; l < 8; ++l) {
            clo += wgt[l] * bflo(hsr[bb][l][e]);
            chi += wgt[l] * bfhi(hsr[bb][l][e]);
          }
          unsigned cw = packbf(clo * inv, chi * inv);
          unsigned* d1 = (unsigned*)(dst + 512 + lane * 2 + 128 * e);
          unsigned* d0 = (unsigned*)(dst + lane * 2 + 128 * e);
          asm volatile("global_store_dword %0, %1, off sc0 sc1" :: "v"(d1), "v"(cw) : "memory");
          asm volatile("global_store_dword %0, %1, off sc0 sc1" :: "v"(d0), "v"(hatt[bb][e]) : "memory");
        }
      }
      asm volatile("s_waitcnt vmcnt(0)" ::: "memory");
      __syncthreads();
      if (tid == 0)
        __hip_atomic_fetch_add(ctl + 1056 + tp * 32, 1u, __ATOMIC_RELAXED, __HIP_MEMORY_SCOPE_AGENT);
      __syncthreads();
    }

  } else {
    // ===================== GEMM workers =====================
    const int w2 = blockIdx.x - NBLK_REC - NBLK_ATT;   // 0..191
    const int fr = lane & 15, ku = lane >> 4;
    const int fq = (lane >> 4) * 4;
    bf16* AsW = (bf16*)pool;             // 8 KB
    bf16* BsW = (bf16*)(pool + 8192);    // 8 KB
    bf16* Tb  = (bf16*)(pool + 16384);   // 32 KB transpose bounce (phase 1)
    const int wm = (wid >> 1) * 64, wn = (wid & 1) * 64;

    auto wait_ge = [&](unsigned* p, unsigned target) {
      if (tid == 0) {
        unsigned v; int it = 0;
        do {
          asm volatile("global_load_dword %0, %1, off sc0 sc1\ns_waitcnt vmcnt(0)"
                       : "=v"(v) : "v"(p) : "memory");
          if (v >= target) break;
          __builtin_amdgcn_s_sleep(8);
        } while (++it < (1 << 20));
      }
      __syncthreads();
    };

    // ---- phase 1: preDec pre-gate tiles (768 tiles over 192 workers) ----
    for (int i = w2; i < 768; i += NWG) {
      int t = i >> 4, tn = i & 15;
      int m0 = t * 128, n0 = tn * 128;
      f32x4 acc[4][4];
      #pragma unroll
      for (int mi = 0; mi < 4; ++mi)
        #pragma unroll
        for (int ni = 0; ni < 4; ++ni) {
          acc[mi][ni][0] = 0.f; acc[mi][ni][1] = 0.f;
          acc[mi][ni][2] = 0.f; acc[mi][ni][3] = 0.f;
        }
      for (int kt = 0; kt < 512; kt += 32) {
        #pragma unroll
        for (int j = 0; j < 2; ++j) {
          int i0 = j * 256 + wid * 64;
          int ii = i0 + lane;
          int r = ii >> 2, q = ii & 3;
          gl_lds16(Xdec + (size_t)(m0 + r) * 512 + kt + q * 8, AsW + (size_t)i0 * 8);
          gl_lds16(WihD + (size_t)(n0 + r) * 512 + kt + q * 8, BsW + (size_t)i0 * 8);
        }
        __syncthreads();
        bf16x8 af[4], bfr[4];
        #pragma unroll
        for (int mi = 0; mi < 4; ++mi)
          af[mi] = *(const bf16x8*)(AsW + (size_t)(wm + mi * 16 + fr) * 32 + ku * 8);
        #pragma unroll
        for (int ni = 0; ni < 4; ++ni)
          bfr[ni] = *(const bf16x8*)(BsW + (size_t)(wn + ni * 16 + fr) * 32 + ku * 8);
        #pragma unroll
        for (int mi = 0; mi < 4; ++mi)
          #pragma unroll
          for (int ni = 0; ni < 4; ++ni)
            acc[mi][ni] = __builtin_amdgcn_mfma_f32_16x16x32_bf16(af[mi], bfr[ni], acc[mi][ni], 0, 0, 0);
        __syncthreads();
      }
      #pragma unroll
      for (int mi = 0; mi < 4; ++mi)
        #pragma unroll
        for (int ni = 0; ni < 4; ++ni) {
          int cl = wn + ni * 16 + fr;
          float bias = db[n0 + cl];
          #pragma unroll
          for (int j = 0; j < 4; ++j)
            Tb[(size_t)cl * 128 + (wm + mi * 16 + fq + j)] = (bf16)(acc[mi][ni][j] + bias);
        }
      __syncthreads();
      #pragma unroll
      for (int rep = 0; rep < 8; ++rep) {
        int u = rep * 256 + tid;
        int cl = u >> 4, cb = u & 15;
        f32x4 v = *(f32x4*)(Tb + (size_t)cl * 128 + cb * 8);
        bf16* dst = preDecT + ((size_t)t * 2048 + n0 + cl) * 128 + cb * 8;
        asm volatile("global_store_dwordx4 %0, %1, off sc0 sc1" :: "v"(dst), "v"(v) : "memory");
      }
      asm volatile("s_waitcnt vmcnt(0)" ::: "memory");
      __syncthreads();
      if (tid == 0)
        __hip_atomic_fetch_add(ctl + 1024, 1u, __ATOMIC_RELAXED, __HIP_MEMORY_SCOPE_AGENT);
      __syncthreads();
    }

    // ---- phase 2: n-band output projection ----
    // worker w2<158: n-band = w2>>1, t parity = w2&1 -> 24 tiles, B L2-resident.
    if (w2 >= 158) return;
    const int n = w2 >> 1, tpar = w2 & 1;
    const int n0 = n * 128;
    for (int t = tpar; t < 48; t += 2) {
      wait_ge(ctl + 1056 + t * 32, (unsigned)NBLK_ATT);
      const bf16* Abase = Hcat + (size_t)t * 131072;
      f32x4 acc[4][4];
      #pragma unroll
      for (int mi = 0; mi < 4; ++mi)
        #pragma unroll
        for (int ni = 0; ni < 4; ++ni) {
          acc[mi][ni][0] = 0.f; acc[mi][ni][1] = 0.f;
          acc[mi][ni][2] = 0.f; acc[mi][ni][3] = 0.f;
        }
      for (int kt = 0; kt < 1024; kt += 32) {
        #pragma unroll
        for (int j = 0; j < 2; ++j) {
          int i0 = j * 256 + wid * 64;
          int ii = i0 + lane;
          int r = ii >> 2, q = ii & 3;
          gl_lds16(Abase + (size_t)r * 1024 + kt + q * 8, AsW + (size_t)i0 * 8);
          gl_lds16(outWb + (size_t)(n0 + r) * 1024 + kt + q * 8, BsW + (size_t)i0 * 8);
        }
        __syncthreads();
        bf16x8 af[4], bfr[4];
        #pragma unroll
        for (int mi = 0; mi < 4; ++mi)
          af[mi] = *(const bf16x8*)(AsW + (size_t)(wm + mi * 16 + fr) * 32 + ku * 8);
        #pragma unroll
        for (int ni = 0; ni < 4; ++ni)
          bfr[ni] = *(const bf16x8*)(BsW + (size_t)(wn + ni * 16 + fr) * 32 + ku * 8);
        #pragma unroll
        for (int mi = 0; mi < 4; ++mi)
          #pragma unroll
          for (int ni = 0; ni < 4; ++ni)
            acc[mi][ni] = __builtin_amdgcn_mfma_f32_16x16x32_bf16(af[mi], bfr[ni], acc[mi][ni], 0, 0, 0);
        __syncthreads();
      }
      #pragma unroll
      for (int mi = 0; mi < 4; ++mi) {
        #pragma unroll
        for (int ni = 0; ni < 4; ++ni) {
          int cix = n0 + wn + ni * 16 + fr;
          if (cix < V_) {
            float bias = outb[cix];
            #pragma unroll
            for (int j = 0; j < 4; ++j) {
              int b = wm + mi * 16 + fq + j;
              out[(size_t)b * (T_ * V_) + (size_t)t * V_ + cix] = acc[mi][ni][j] + bias;
            }
          }
        }
      }
    }
  }
}

// ---------------------------------------------------------------------------
extern "C" void kernel_launch(void* const* d_in, const int* in_sizes, int n_in,
                              void* d_out, int out_size, void* d_ws, size_t ws_size,
                              hipStream_t stream)
{
  const int* kws  = (const int*)d_in[0];
  const int* poem = (const int*)d_in[1];
  const int* kwl  = (const int*)d_in[2];
  const float* emb  = (const float*)d_in[3];
  const float* eWih = (const float*)d_in[4];
  const float* eWhh = (const float*)d_in[5];
  const float* eb   = (const float*)d_in[6];
  const float* dWih = (const float*)d_in[7];
  const float* dWhh = (const float*)d_in[8];
  const float* db   = (const float*)d_in[9];
  const float* outW = (const float*)d_in[10];
  const float* outb = (const float*)d_in[11];
  float* out = (float*)d_out;

  char* base = (char*)d_ws;
  size_t o = 0;
  auto take = [&](size_t bytes) -> char* {
    char* r = base + o;
    o += (bytes + 255) & ~(size_t)255;
    return r;
  };
  bf16* WihE  = (bf16*)take(2048 * 512 * 2);
  bf16* WhhE  = (bf16*)take(2048 * 512 * 2);
  bf16* WihD  = (bf16*)take(2048 * 512 * 2);
  bf16* WhhD  = (bf16*)take(2048 * 512 * 2);
  bf16* outWb = (bf16*)take((size_t)10112 * 1024 * 2);
  bf16* Xenc  = (bf16*)take(1024 * 512 * 2);
  bf16* Xdec  = (bf16*)take((size_t)6144 * 512 * 2);
  bf16* preEncT = (bf16*)take((size_t)8 * 2048 * 128 * 2);
  bf16* preDecT = (bf16*)take((size_t)48 * 2048 * 128 * 2);
  bf16* Hcat   = (bf16*)take((size_t)6144 * 1024 * 2);
  bf16* hS     = (bf16*)take((size_t)56 * 65536 * 2);
  bf16* hsEnc  = (bf16*)take((size_t)8 * 128 * 512 * 2);
  bf16* h0b    = (bf16*)take(128 * 512 * 2);
  unsigned* ctl = (unsigned*)take(32768);

  prep_kernel<<<4096, 256, 0, stream>>>(kws, poem, emb, eWih, eWhh, dWih, dWhh, outW,
                                        WihE, WhhE, WihD, WhhD, outWb, Xenc, Xdec, ctl);

  // encoder pre-gates (needed at recurrence step 0)
  gemm_pre_kernel<<<128, 256, 0, stream>>>(Xenc, WihE, eb, preEncT, 1024, 2048, 512, 8);

  // fused: recurrence + attention workers + preDec pre-gates + projection
  fused_kernel<<<NBLK_TOT, 256, 0, stream>>>(preEncT, preDecT, WhhE, WhhD, kwl,
                                             hS, h0b, hsEnc, Hcat,
                                             Xdec, WihD, db, outWb, outb, out, ctl);
}